// Round 1
// 111.563 us; speedup vs baseline: 1.1075x; 1.1075x over previous
//
#include <hip/hip_runtime.h>

#define N 1024
#define DIM 128
#define TI 4       // rows per attn block
#define JCH 256    // j's per attn block
#define NCH 4      // number of j-chunks (N / JCH)
#define SC 16      // j sub-chunk per loop iter
#define NSC 16     // JCH / SC

// ---- DPP 32-lane sum (VALU pipe): group sums land in wave lanes 31 / 63 ----
template <int CTRL>
__device__ __forceinline__ float dpp_add(float x) {
  int y = __builtin_amdgcn_update_dpp(0, __float_as_int(x), CTRL, 0xF, 0xF, true);
  return x + __int_as_float(y);
}
__device__ __forceinline__ float red32(float x) {
  x = dpp_add<0x111>(x);  // row_shr:1
  x = dpp_add<0x112>(x);  // row_shr:2
  x = dpp_add<0x114>(x);  // row_shr:4
  x = dpp_add<0x118>(x);  // row_shr:8
  x = dpp_add<0x142>(x);  // row_bcast15 -> lanes 31/63 have their 32-lane sums
  return x;
}

// Broadcast from lane 31 (lo half) / 63 (hi half): single LDS-pipe op,
// replaces 2x v_readlane + v_cndmask on the VALU pipe.
__device__ __forceinline__ float bperm(int baddr, float x) {
  return __int_as_float(__builtin_amdgcn_ds_bpermute(baddr, __float_as_int(x)));
}

// e-partial that KEEPS the relu values in registers for the R-accumulation
// (removes the add+max recompute: 8 -> 6 ops per (i,j,d) element).
__device__ __forceinline__ float epart_keep(const float4 q, const float4 k,
                                            const float4 w, float4* relu) {
  const float rx = fmaxf(q.x + k.x, 0.f);
  const float ry = fmaxf(q.y + k.y, 0.f);
  const float rz = fmaxf(q.z + k.z, 0.f);
  const float rw = fmaxf(q.w + k.w, 0.f);
  relu->x = rx; relu->y = ry; relu->z = rz; relu->w = rw;
  float a = rx * w.x;
  a = fmaf(ry, w.y, a);
  a = fmaf(rz, w.z, a);
  a = fmaf(rw, w.w, a);
  return a;
}

__device__ __forceinline__ void accum_rs(float p, const float4 relu,
                                         const float4 v, float4* R, float4* S) {
  R->x = fmaf(p, relu.x, R->x);
  R->y = fmaf(p, relu.y, R->y);
  R->z = fmaf(p, relu.z, R->z);
  R->w = fmaf(p, relu.w, R->w);
  S->x = fmaf(p, v.x, S->x);
  S->y = fmaf(p, v.y, S->y);
  S->z = fmaf(p, v.z, S->z);
  S->w = fmaf(p, v.w, S->w);
}

// ------------------------------------------------------------------
// Kernel 1: QKV. 4 rows/block, 512 threads, W read ONCE per block
// (old version had 2x intra-block redundancy: 196 MB L2 -> 49 MB).
// ------------------------------------------------------------------
__global__ __launch_bounds__(512) void qkv_kernel3(
    const float* __restrict__ x,
    const float* __restrict__ WQ, const float* __restrict__ bQ,
    const float* __restrict__ WK, const float* __restrict__ bK,
    const float* __restrict__ WV, const float* __restrict__ bV,
    float* __restrict__ Q, float* __restrict__ K, float* __restrict__ V) {
  const int i0 = blockIdx.x * 4;
  const int t = threadIdx.x;
  const int dq = t & 31;   // output d-quad
  const int qr = t >> 5;   // column group 0..15 (8 columns each)

  __shared__ __align__(16) float xs[4][DIM];
  __shared__ __align__(16) float pacc[16][3][4][DIM];  // 96 KB

  if (t < 128) {
    const int row = t >> 5, c4 = t & 31;
    ((float4*)&xs[row][0])[c4] = ((const float4*)(x + (i0 + row) * DIM))[c4];
  }
  __syncthreads();

  const float4* WQ4 = (const float4*)WQ;
  const float4* WK4 = (const float4*)WK;
  const float4* WV4 = (const float4*)WV;
  float4 aQ[4], aK[4], aV[4];
#pragma unroll
  for (int r = 0; r < 4; ++r) {
    aQ[r] = make_float4(0.f, 0.f, 0.f, 0.f);
    aK[r] = make_float4(0.f, 0.f, 0.f, 0.f);
    aV[r] = make_float4(0.f, 0.f, 0.f, 0.f);
  }
  const int c0 = qr * 8;
#pragma unroll 2
  for (int cc = 0; cc < 8; ++cc) {
    const int c = c0 + cc;
    const float4 wq = WQ4[c * 32 + dq];
    const float4 wk = WK4[c * 32 + dq];
    const float4 wv = WV4[c * 32 + dq];
#pragma unroll
    for (int r = 0; r < 4; ++r) {
      const float xv = xs[r][c];
      aQ[r].x = fmaf(xv, wq.x, aQ[r].x); aQ[r].y = fmaf(xv, wq.y, aQ[r].y);
      aQ[r].z = fmaf(xv, wq.z, aQ[r].z); aQ[r].w = fmaf(xv, wq.w, aQ[r].w);
      aK[r].x = fmaf(xv, wk.x, aK[r].x); aK[r].y = fmaf(xv, wk.y, aK[r].y);
      aK[r].z = fmaf(xv, wk.z, aK[r].z); aK[r].w = fmaf(xv, wk.w, aK[r].w);
      aV[r].x = fmaf(xv, wv.x, aV[r].x); aV[r].y = fmaf(xv, wv.y, aV[r].y);
      aV[r].z = fmaf(xv, wv.z, aV[r].z); aV[r].w = fmaf(xv, wv.w, aV[r].w);
    }
  }
#pragma unroll
  for (int r = 0; r < 4; ++r) {
    ((float4*)&pacc[qr][0][r][0])[dq] = aQ[r];
    ((float4*)&pacc[qr][1][r][0])[dq] = aK[r];
    ((float4*)&pacc[qr][2][r][0])[dq] = aV[r];
  }
  __syncthreads();
  {
    const int row = (t >> 7) & 3, d = t & 127;
#pragma unroll
    for (int m = 0; m < 3; ++m) {
      float s = 0.f;
#pragma unroll
      for (int c = 0; c < 16; ++c) s += pacc[c][m][row][d];
      float* dst = (m == 0) ? Q : (m == 1) ? K : V;
      const float* bias = (m == 0) ? bQ : (m == 1) ? bK : bV;
      dst[(i0 + row) * DIM + d] = s + bias[d];
    }
  }
}

// ------------------------------------------------------------------
// Kernel 2: barrier-free hot loop. Two phases per iter (kc0 then kc1)
// so relu temps are reused across e/R with only +16 live VGPRs.
// W_A pre-scaled by log2(e) -> raw v_exp (exp2), no per-value mul.
// ------------------------------------------------------------------
__global__ __launch_bounds__(256) void attn_fused5(
    const float* __restrict__ Q, const float* __restrict__ K,
    const float* __restrict__ V, const float* __restrict__ WA,
    float* __restrict__ Rw, float* __restrict__ Sw, float* __restrict__ Lw) {
  const int bi = blockIdx.x >> 2;
  const int jc = blockIdx.x & 3;
  const int i0 = bi * TI;
  const int j0 = jc * JCH;
  const int t = threadIdx.x;
  const int dq = t & 31;           // d-quad lane
  const int f = t >> 5;            // j-group 0..7
  const int baddr = (t & 32) ? (63 << 2) : (31 << 2);

  __shared__ __align__(16) float red_s[2][8 * TI * DIM];  // 32 KB epilogue buf
  __shared__ __align__(16) float4 lred4[8];

  float4 wa4 = ((const float4*)WA)[dq];
  const float LOG2E = 1.44269504088896340736f;
  wa4.x *= LOG2E; wa4.y *= LOG2E; wa4.z *= LOG2E; wa4.w *= LOG2E;

  float4 q4[TI];
#pragma unroll
  for (int r = 0; r < TI; ++r)
    q4[r] = ((const float4*)(Q + (i0 + r) * DIM))[dq];

  float4 Racc[TI], Sacc[TI];
#pragma unroll
  for (int r = 0; r < TI; ++r) {
    Racc[r] = make_float4(0.f, 0.f, 0.f, 0.f);
    Sacc[r] = make_float4(0.f, 0.f, 0.f, 0.f);
  }
  float4 lacc = make_float4(0.f, 0.f, 0.f, 0.f);

  const float4* K4 = (const float4*)K;
  const float4* V4 = (const float4*)V;
  float4 kc0 = K4[(j0 + f) * 32 + dq];
  float4 kc1 = K4[(j0 + 8 + f) * 32 + dq];
  float4 vc0 = V4[(j0 + f) * 32 + dq];
  float4 vc1 = V4[(j0 + 8 + f) * 32 + dq];

  for (int sc = 0; sc < NSC; ++sc) {
    // ---- phase A: e-partials for kc0, relu kept live ----
    float4 reluA0, reluA1, reluA2, reluA3;
    float4 peA;
    peA.x = epart_keep(q4[0], kc0, wa4, &reluA0);
    peA.y = epart_keep(q4[1], kc0, wa4, &reluA1);
    peA.z = epart_keep(q4[2], kc0, wa4, &reluA2);
    peA.w = epart_keep(q4[3], kc0, wa4, &reluA3);

    // ---- prefetch next sub-chunk (hides L2 latency under reductions) ----
    const int scn = (sc + 1 < NSC) ? sc + 1 : sc;
    const int jb = j0 + scn * SC;
    const float4 kn0 = K4[(jb + f) * 32 + dq];
    const float4 kn1 = K4[(jb + 8 + f) * 32 + dq];
    const float4 vn0 = V4[(jb + f) * 32 + dq];
    const float4 vn1 = V4[(jb + 8 + f) * 32 + dq];

    peA.x = red32(peA.x); peA.y = red32(peA.y);
    peA.z = red32(peA.z); peA.w = red32(peA.w);
    float4 pA;
    pA.x = __builtin_amdgcn_exp2f(bperm(baddr, peA.x));
    pA.y = __builtin_amdgcn_exp2f(bperm(baddr, peA.y));
    pA.z = __builtin_amdgcn_exp2f(bperm(baddr, peA.z));
    pA.w = __builtin_amdgcn_exp2f(bperm(baddr, peA.w));

    accum_rs(pA.x, reluA0, vc0, &Racc[0], &Sacc[0]);
    accum_rs(pA.y, reluA1, vc0, &Racc[1], &Sacc[1]);
    accum_rs(pA.z, reluA2, vc0, &Racc[2], &Sacc[2]);
    accum_rs(pA.w, reluA3, vc0, &Racc[3], &Sacc[3]);
    lacc.x += pA.x; lacc.y += pA.y; lacc.z += pA.z; lacc.w += pA.w;

    // ---- phase B: same for kc1 ----
    float4 reluB0, reluB1, reluB2, reluB3;
    float4 peB;
    peB.x = epart_keep(q4[0], kc1, wa4, &reluB0);
    peB.y = epart_keep(q4[1], kc1, wa4, &reluB1);
    peB.z = epart_keep(q4[2], kc1, wa4, &reluB2);
    peB.w = epart_keep(q4[3], kc1, wa4, &reluB3);

    peB.x = red32(peB.x); peB.y = red32(peB.y);
    peB.z = red32(peB.z); peB.w = red32(peB.w);
    float4 pB;
    pB.x = __builtin_amdgcn_exp2f(bperm(baddr, peB.x));
    pB.y = __builtin_amdgcn_exp2f(bperm(baddr, peB.y));
    pB.z = __builtin_amdgcn_exp2f(bperm(baddr, peB.z));
    pB.w = __builtin_amdgcn_exp2f(bperm(baddr, peB.w));

    accum_rs(pB.x, reluB0, vc1, &Racc[0], &Sacc[0]);
    accum_rs(pB.y, reluB1, vc1, &Racc[1], &Sacc[1]);
    accum_rs(pB.z, reluB2, vc1, &Racc[2], &Sacc[2]);
    accum_rs(pB.w, reluB3, vc1, &Racc[3], &Sacc[3]);
    lacc.x += pB.x; lacc.y += pB.y; lacc.z += pB.z; lacc.w += pB.w;

    kc0 = kn0; kc1 = kn1; vc0 = vn0; vc1 = vn1;
  }

  // ---- epilogue: both R and S staged at once (one sync round) ----
  float4* F4r = (float4*)&red_s[0][0];
  float4* F4s = (float4*)&red_s[1][0];
#pragma unroll
  for (int r = 0; r < TI; ++r) {
    F4r[(f * 4 + r) * 32 + dq] = Racc[r];
    F4s[(f * 4 + r) * 32 + dq] = Sacc[r];
  }
  if (dq == 0) lred4[f] = lacc;
  __syncthreads();
#pragma unroll
  for (int p = 0; p < 4; ++p) {
    const int o = t + 256 * p;       // 0..1023
    const int m = o >> 9;            // 0: R, 1: S (wave-uniform)
    const int r = (o >> 7) & 3;
    const int d = o & 127;
    float acc = 0.f;
#pragma unroll
    for (int c = 0; c < 8; ++c) acc += red_s[m][(c * 4 + r) * 128 + d];
    float* dst = m ? Sw : Rw;
    dst[(jc * N + i0 + r) * DIM + d] = acc;
  }
  if (t < TI) {
    float l = 0.f;
#pragma unroll
    for (int c = 0; c < 8; ++c) l += ((const float*)&lred4[c])[t];
    Lw[jc * N + i0 + t] = l;
  }
}

// ------------------------------------------------------------------
// Kernel 3: combine. 2 rows/block (512 blocks) -> WEv L2 traffic
// halves (64 -> 32 MB); NCH=4 partial chunks.
// ------------------------------------------------------------------
__global__ __launch_bounds__(256) void attn_combine5(
    const float* __restrict__ WEv, const float* __restrict__ bEv,
    const float* __restrict__ Rw, const float* __restrict__ Sw,
    const float* __restrict__ Lw, float* __restrict__ out) {
  const int i0 = blockIdx.x * 2;
  const int t = threadIdx.x;

  __shared__ __align__(16) float Rst[2][DIM];
  __shared__ __align__(16) float Sst[2][DIM];
  __shared__ __align__(16) float4 Eacc4[8][2][DIM / 4];  // 8 KB
  __shared__ float linv_s[2];

  // step 1: L (lanes 0..7 of wave 0: 2 rows x 4 chunks)
  if (t < 8) {
    const int row = t >> 2, c = t & 3;
    float l = Lw[c * N + i0 + row];
    l += __shfl_xor(l, 1, 4);
    l += __shfl_xor(l, 2, 4);
    if (c == 0) linv_s[row] = 1.0f / l;
  }

  // step 2: R*, S* (512 sums over 256 threads; coalesced over d)
#pragma unroll
  for (int p = 0; p < 2; ++p) {
    const int o = t + 256 * p;
    const int d = o & 127;
    const int set = o >> 7;  // 0..3, wave-uniform
    const int row = set & 1;
    const int mat = set >> 1;
    const float* src = mat ? Sw : Rw;
    float acc = 0.f;
#pragma unroll
    for (int c = 0; c < NCH; ++c) acc += src[(c * N + i0 + row) * DIM + d];
    if (mat) Sst[row][d] = acc; else Rst[row][d] = acc;
  }
  __syncthreads();

  // step 3: matvec R* @ WEv for both rows sharing one WEv load
  {
    const int dq = t & 31;   // output d-quad
    const int qr = t >> 5;   // dp-eighth 0..7
    const float4* WEv4 = (const float4*)WEv;
    float4 a0 = make_float4(0.f, 0.f, 0.f, 0.f);
    float4 a1 = make_float4(0.f, 0.f, 0.f, 0.f);
    const int dp0 = 16 * qr;
#pragma unroll 8
    for (int dp = dp0; dp < dp0 + 16; ++dp) {
      const float4 w4 = WEv4[dp * 32 + dq];  // coalesced float4
      const float r0 = Rst[0][dp];           // LDS broadcast
      const float r1 = Rst[1][dp];
      a0.x = fmaf(r0, w4.x, a0.x); a0.y = fmaf(r0, w4.y, a0.y);
      a0.z = fmaf(r0, w4.z, a0.z); a0.w = fmaf(r0, w4.w, a0.w);
      a1.x = fmaf(r1, w4.x, a1.x); a1.y = fmaf(r1, w4.y, a1.y);
      a1.z = fmaf(r1, w4.z, a1.z); a1.w = fmaf(r1, w4.w, a1.w);
    }
    Eacc4[qr][0][dq] = a0;
    Eacc4[qr][1][dq] = a1;
  }
  __syncthreads();

  // step 4: reduce eighths + normalize + bias + store (1 output/thread)
  {
    const int row = t >> 7, d = t & 127;
    const int dq = d >> 2, e = d & 3;
    float acc = Sst[row][d];
#pragma unroll
    for (int qr = 0; qr < 8; ++qr)
      acc += ((const float*)&Eacc4[qr][row][dq])[e];
    out[(i0 + row) * DIM + d] = fmaf(acc, linv_s[row], bEv[d]);
  }
}

// ------------------------------------------------------------------
// Fallback (round-1 proven kernel) if ws is too small for partials.
// ------------------------------------------------------------------
__global__ __launch_bounds__(256) void attn_fallback(
    const float* __restrict__ Q, const float* __restrict__ K,
    const float* __restrict__ V, const float* __restrict__ WA,
    const float* __restrict__ WEv, const float* __restrict__ bEv,
    float* __restrict__ out) {
  const int i = blockIdx.x;
  const int t = threadIdx.x;

  __shared__ __align__(16) float qs[DIM];
  __shared__ __align__(16) float was[DIM];
  __shared__ __align__(16) float p[N];
  __shared__ float red[256];
  __shared__ __align__(16) float Rs[8][DIM];
  __shared__ __align__(16) float Ss[8][DIM];

  if (t < DIM) {
    qs[t] = Q[i * DIM + t];
    was[t] = WA[t];
  }
  __syncthreads();

  float evals[4];
  float mloc = -3.4e38f;
  for (int jj = 0; jj < 4; ++jj) {
    const int j = t + jj * 256;
    const float4* krow = (const float4*)(K + j * DIM);
    const float4* q4p = (const float4*)qs;
    const float4* w4p = (const float4*)was;
    float acc = 0.f;
    for (int d4 = 0; d4 < DIM / 4; ++d4) {
      const float4 k4 = krow[d4];
      const float4 q4 = q4p[d4];
      const float4 w4 = w4p[d4];
      acc = fmaf(fmaxf(q4.x + k4.x, 0.f), w4.x, acc);
      acc = fmaf(fmaxf(q4.y + k4.y, 0.f), w4.y, acc);
      acc = fmaf(fmaxf(q4.z + k4.z, 0.f), w4.z, acc);
      acc = fmaf(fmaxf(q4.w + k4.w, 0.f), w4.w, acc);
    }
    evals[jj] = acc;
    mloc = fmaxf(mloc, acc);
  }
  red[t] = mloc;
  __syncthreads();
  for (int s = 128; s > 0; s >>= 1) {
    if (t < s) red[t] = fmaxf(red[t], red[t + s]);
    __syncthreads();
  }
  const float m = red[0];
  __syncthreads();
  float lsum = 0.f;
  for (int jj = 0; jj < 4; ++jj) {
    const float pe = __expf(evals[jj] - m);
    p[t + jj * 256] = pe;
    lsum += pe;
  }
  red[t] = lsum;
  __syncthreads();
  for (int s = 128; s > 0; s >>= 1) {
    if (t < s) red[t] += red[t + s];
    __syncthreads();
  }
  const float linv = 1.0f / red[0];
  __syncthreads();

  const int tx = t & 31;
  const int ty = t >> 5;
  const float4 q4 = ((const float4*)qs)[tx];
  float4 R4 = make_float4(0.f, 0.f, 0.f, 0.f);
  float4 S4 = make_float4(0.f, 0.f, 0.f, 0.f);
  for (int j = ty; j < N; j += 8) {
    const float pj = p[j];
    const float4 k4 = ((const float4*)(K + j * DIM))[tx];
    const float4 v4 = ((const float4*)(V + j * DIM))[tx];
    R4.x = fmaf(pj, fmaxf(q4.x + k4.x, 0.f), R4.x);
    R4.y = fmaf(pj, fmaxf(q4.y + k4.y, 0.f), R4.y);
    R4.z = fmaf(pj, fmaxf(q4.z + k4.z, 0.f), R4.z);
    R4.w = fmaf(pj, fmaxf(q4.w + k4.w, 0.f), R4.w);
    S4.x = fmaf(pj, v4.x, S4.x);
    S4.y = fmaf(pj, v4.y, S4.y);
    S4.z = fmaf(pj, v4.z, S4.z);
    S4.w = fmaf(pj, v4.w, S4.w);
  }
  ((float4*)&Rs[ty][0])[tx] = R4;
  ((float4*)&Ss[ty][0])[tx] = S4;
  __syncthreads();

  if (t < DIM) {
    float R = 0.f, S = 0.f;
    for (int g = 0; g < 8; ++g) {
      R += Rs[g][t];
      S += Ss[g][t];
    }
    Rs[0][t] = R;
    Ss[0][t] = S;
  }
  __syncthreads();

  if (t < DIM) {
    float o = Ss[0][t];
    for (int dp = 0; dp < DIM; ++dp) {
      o = fmaf(Rs[0][dp], WEv[dp * DIM + t], o);
    }
    out[i * DIM + t] = fmaf(o, linv, bEv[t]);
  }
}

extern "C" void kernel_launch(void* const* d_in, const int* in_sizes, int n_in,
                              void* d_out, int out_size, void* d_ws, size_t ws_size,
                              hipStream_t stream) {
  const float* x    = (const float*)d_in[0];
  const float* W_Q  = (const float*)d_in[1];
  const float* b_Q  = (const float*)d_in[2];
  const float* W_K  = (const float*)d_in[3];
  const float* b_K  = (const float*)d_in[4];
  const float* W_V  = (const float*)d_in[5];
  const float* b_V  = (const float*)d_in[6];
  const float* W_Ev = (const float*)d_in[7];
  const float* b_Ev = (const float*)d_in[8];
  const float* W_A  = (const float*)d_in[9];
  // d_in[10] = b_A: constant shift under softmax — drops out exactly.

  float* Q = (float*)d_ws;            // N*DIM
  float* K = Q + N * DIM;             // N*DIM
  float* V = K + N * DIM;             // N*DIM
  float* out = (float*)d_out;

  const size_t need_floats = (size_t)3 * N * DIM + (size_t)2 * NCH * N * DIM +
                             (size_t)NCH * N;

  qkv_kernel3<<<N / 4, 512, 0, stream>>>(x, W_Q, b_Q, W_K, b_K, W_V, b_V, Q, K, V);

  if (ws_size >= need_floats * sizeof(float)) {
    float* Rw = V + N * DIM;            // NCH*N*DIM
    float* Sw = Rw + NCH * N * DIM;     // NCH*N*DIM
    float* Lw = Sw + NCH * N * DIM;     // NCH*N
    attn_fused5<<<(N / TI) * NCH, 256, 0, stream>>>(Q, K, V, W_A, Rw, Sw, Lw);
    attn_combine5<<<N / 2, 256, 0, stream>>>(W_Ev, b_Ev, Rw, Sw, Lw, out);
  } else {
    attn_fallback<<<N, 256, 0, stream>>>(Q, K, V, W_A, W_Ev, b_Ev, out);
  }
}

// Round 2
// 111.035 us; speedup vs baseline: 1.1127x; 1.0047x over previous
//
#include <hip/hip_runtime.h>

#define N 1024
#define DIM 128
#define TI 4       // rows per attn block
#define JCH 256    // j's per attn block
#define NCH 4      // number of j-chunks (N / JCH)
#define SC 16      // j sub-chunk per loop iter
#define NSC 16     // JCH / SC

// ---- DPP 32-lane sum (VALU pipe): group sums land in wave lanes 31 / 63 ----
template <int CTRL>
__device__ __forceinline__ float dpp_add(float x) {
  int y = __builtin_amdgcn_update_dpp(0, __float_as_int(x), CTRL, 0xF, 0xF, true);
  return x + __int_as_float(y);
}
__device__ __forceinline__ float red32(float x) {
  x = dpp_add<0x111>(x);  // row_shr:1
  x = dpp_add<0x112>(x);  // row_shr:2
  x = dpp_add<0x114>(x);  // row_shr:4
  x = dpp_add<0x118>(x);  // row_shr:8
  x = dpp_add<0x142>(x);  // row_bcast15 -> lanes 31/63 have their 32-lane sums
  return x;
}

// Broadcast from lane 31 (lo half) / 63 (hi half): single LDS-pipe op.
__device__ __forceinline__ float bperm(int baddr, float x) {
  return __int_as_float(__builtin_amdgcn_ds_bpermute(baddr, __float_as_int(x)));
}

// e-partial that KEEPS the relu values in registers for the R-accumulation.
__device__ __forceinline__ float epart_keep(const float4 q, const float4 k,
                                            const float4 w, float4* relu) {
  const float rx = fmaxf(q.x + k.x, 0.f);
  const float ry = fmaxf(q.y + k.y, 0.f);
  const float rz = fmaxf(q.z + k.z, 0.f);
  const float rw = fmaxf(q.w + k.w, 0.f);
  relu->x = rx; relu->y = ry; relu->z = rz; relu->w = rw;
  float a = rx * w.x;
  a = fmaf(ry, w.y, a);
  a = fmaf(rz, w.z, a);
  a = fmaf(rw, w.w, a);
  return a;
}

__device__ __forceinline__ void accum_rs(float p, const float4 relu,
                                         const float4 v, float4* R, float4* S) {
  R->x = fmaf(p, relu.x, R->x);
  R->y = fmaf(p, relu.y, R->y);
  R->z = fmaf(p, relu.z, R->z);
  R->w = fmaf(p, relu.w, R->w);
  S->x = fmaf(p, v.x, S->x);
  S->y = fmaf(p, v.y, S->y);
  S->z = fmaf(p, v.z, S->z);
  S->w = fmaf(p, v.w, S->w);
}

// ------------------------------------------------------------------
// Kernel 1: QKV. 4 rows/block, 512 threads, W read ONCE per block.
// ------------------------------------------------------------------
__global__ __launch_bounds__(512) void qkv_kernel3(
    const float* __restrict__ x,
    const float* __restrict__ WQ, const float* __restrict__ bQ,
    const float* __restrict__ WK, const float* __restrict__ bK,
    const float* __restrict__ WV, const float* __restrict__ bV,
    float* __restrict__ Q, float* __restrict__ K, float* __restrict__ V) {
  const int i0 = blockIdx.x * 4;
  const int t = threadIdx.x;
  const int dq = t & 31;   // output d-quad
  const int qr = t >> 5;   // column group 0..15 (8 columns each)

  __shared__ __align__(16) float xs[4][DIM];
  __shared__ __align__(16) float pacc[16][3][4][DIM];  // 96 KB

  if (t < 128) {
    const int row = t >> 5, c4 = t & 31;
    ((float4*)&xs[row][0])[c4] = ((const float4*)(x + (i0 + row) * DIM))[c4];
  }
  __syncthreads();

  const float4* WQ4 = (const float4*)WQ;
  const float4* WK4 = (const float4*)WK;
  const float4* WV4 = (const float4*)WV;
  float4 aQ[4], aK[4], aV[4];
#pragma unroll
  for (int r = 0; r < 4; ++r) {
    aQ[r] = make_float4(0.f, 0.f, 0.f, 0.f);
    aK[r] = make_float4(0.f, 0.f, 0.f, 0.f);
    aV[r] = make_float4(0.f, 0.f, 0.f, 0.f);
  }
  const int c0 = qr * 8;
#pragma unroll 2
  for (int cc = 0; cc < 8; ++cc) {
    const int c = c0 + cc;
    const float4 wq = WQ4[c * 32 + dq];
    const float4 wk = WK4[c * 32 + dq];
    const float4 wv = WV4[c * 32 + dq];
#pragma unroll
    for (int r = 0; r < 4; ++r) {
      const float xv = xs[r][c];
      aQ[r].x = fmaf(xv, wq.x, aQ[r].x); aQ[r].y = fmaf(xv, wq.y, aQ[r].y);
      aQ[r].z = fmaf(xv, wq.z, aQ[r].z); aQ[r].w = fmaf(xv, wq.w, aQ[r].w);
      aK[r].x = fmaf(xv, wk.x, aK[r].x); aK[r].y = fmaf(xv, wk.y, aK[r].y);
      aK[r].z = fmaf(xv, wk.z, aK[r].z); aK[r].w = fmaf(xv, wk.w, aK[r].w);
      aV[r].x = fmaf(xv, wv.x, aV[r].x); aV[r].y = fmaf(xv, wv.y, aV[r].y);
      aV[r].z = fmaf(xv, wv.z, aV[r].z); aV[r].w = fmaf(xv, wv.w, aV[r].w);
    }
  }
#pragma unroll
  for (int r = 0; r < 4; ++r) {
    ((float4*)&pacc[qr][0][r][0])[dq] = aQ[r];
    ((float4*)&pacc[qr][1][r][0])[dq] = aK[r];
    ((float4*)&pacc[qr][2][r][0])[dq] = aV[r];
  }
  __syncthreads();
  {
    const int row = (t >> 7) & 3, d = t & 127;
#pragma unroll
    for (int m = 0; m < 3; ++m) {
      float s = 0.f;
#pragma unroll
      for (int c = 0; c < 16; ++c) s += pacc[c][m][row][d];
      float* dst = (m == 0) ? Q : (m == 1) ? K : V;
      const float* bias = (m == 0) ? bQ : (m == 1) ? bK : bV;
      dst[(i0 + row) * DIM + d] = s + bias[d];
    }
  }
}

// ------------------------------------------------------------------
// Kernel 2: barrier-free hot loop. Per-PHASE software pipelining:
// kc dies after epart -> reload in place; vc dies after accum ->
// reload in place. Removes the 4 dedicated prefetch float4 regs
// (-16 VGPR) so __launch_bounds__(256,4) holds 128 VGPR / 4 blk/CU
// without spills. Prefetch distance ~1 phase (~200+ cyc) still
// covers L2 latency.
// ------------------------------------------------------------------
__global__ __launch_bounds__(256, 4) void attn_fused6(
    const float* __restrict__ Q, const float* __restrict__ K,
    const float* __restrict__ V, const float* __restrict__ WA,
    float* __restrict__ Rw, float* __restrict__ Sw, float* __restrict__ Lw) {
  const int bi = blockIdx.x >> 2;
  const int jc = blockIdx.x & 3;
  const int i0 = bi * TI;
  const int j0 = jc * JCH;
  const int t = threadIdx.x;
  const int dq = t & 31;           // d-quad lane
  const int f = t >> 5;            // j-group 0..7
  const int baddr = (t & 32) ? (63 << 2) : (31 << 2);

  __shared__ __align__(16) float red_s[2][8 * TI * DIM];  // 32 KB epilogue buf
  __shared__ __align__(16) float4 lred4[8];

  float4 wa4 = ((const float4*)WA)[dq];
  const float LOG2E = 1.44269504088896340736f;
  wa4.x *= LOG2E; wa4.y *= LOG2E; wa4.z *= LOG2E; wa4.w *= LOG2E;

  float4 q4[TI];
#pragma unroll
  for (int r = 0; r < TI; ++r)
    q4[r] = ((const float4*)(Q + (i0 + r) * DIM))[dq];

  float4 Racc[TI], Sacc[TI];
#pragma unroll
  for (int r = 0; r < TI; ++r) {
    Racc[r] = make_float4(0.f, 0.f, 0.f, 0.f);
    Sacc[r] = make_float4(0.f, 0.f, 0.f, 0.f);
  }
  float4 lacc = make_float4(0.f, 0.f, 0.f, 0.f);

  const float4* K4 = (const float4*)K;
  const float4* V4 = (const float4*)V;
  float4 kc0 = K4[(j0 + f) * 32 + dq];
  float4 kc1 = K4[(j0 + 8 + f) * 32 + dq];
  float4 vc0 = V4[(j0 + f) * 32 + dq];
  float4 vc1 = V4[(j0 + 8 + f) * 32 + dq];

  for (int sc = 0; sc < NSC; ++sc) {
    // next sub-chunk base (last iter re-reads itself: in-bounds, harmless)
    const int jb = j0 + ((sc + 1 < NSC) ? sc + 1 : sc) * SC;

    // ---- phase A ----
    float4 reluA0, reluA1, reluA2, reluA3;
    float4 peA;
    peA.x = epart_keep(q4[0], kc0, wa4, &reluA0);
    peA.y = epart_keep(q4[1], kc0, wa4, &reluA1);
    peA.z = epart_keep(q4[2], kc0, wa4, &reluA2);
    peA.w = epart_keep(q4[3], kc0, wa4, &reluA3);
    kc0 = K4[(jb + f) * 32 + dq];          // kc0 dead -> reload in place

    peA.x = red32(peA.x); peA.y = red32(peA.y);
    peA.z = red32(peA.z); peA.w = red32(peA.w);
    float4 pA;
    pA.x = __builtin_amdgcn_exp2f(bperm(baddr, peA.x));
    pA.y = __builtin_amdgcn_exp2f(bperm(baddr, peA.y));
    pA.z = __builtin_amdgcn_exp2f(bperm(baddr, peA.z));
    pA.w = __builtin_amdgcn_exp2f(bperm(baddr, peA.w));

    accum_rs(pA.x, reluA0, vc0, &Racc[0], &Sacc[0]);
    accum_rs(pA.y, reluA1, vc0, &Racc[1], &Sacc[1]);
    accum_rs(pA.z, reluA2, vc0, &Racc[2], &Sacc[2]);
    accum_rs(pA.w, reluA3, vc0, &Racc[3], &Sacc[3]);
    vc0 = V4[(jb + f) * 32 + dq];          // vc0 dead -> reload in place
    lacc.x += pA.x; lacc.y += pA.y; lacc.z += pA.z; lacc.w += pA.w;

    // ---- phase B ----
    float4 reluB0, reluB1, reluB2, reluB3;
    float4 peB;
    peB.x = epart_keep(q4[0], kc1, wa4, &reluB0);
    peB.y = epart_keep(q4[1], kc1, wa4, &reluB1);
    peB.z = epart_keep(q4[2], kc1, wa4, &reluB2);
    peB.w = epart_keep(q4[3], kc1, wa4, &reluB3);
    kc1 = K4[(jb + 8 + f) * 32 + dq];      // kc1 dead -> reload in place

    peB.x = red32(peB.x); peB.y = red32(peB.y);
    peB.z = red32(peB.z); peB.w = red32(peB.w);
    float4 pB;
    pB.x = __builtin_amdgcn_exp2f(bperm(baddr, peB.x));
    pB.y = __builtin_amdgcn_exp2f(bperm(baddr, peB.y));
    pB.z = __builtin_amdgcn_exp2f(bperm(baddr, peB.z));
    pB.w = __builtin_amdgcn_exp2f(bperm(baddr, peB.w));

    accum_rs(pB.x, reluB0, vc1, &Racc[0], &Sacc[0]);
    accum_rs(pB.y, reluB1, vc1, &Racc[1], &Sacc[1]);
    accum_rs(pB.z, reluB2, vc1, &Racc[2], &Sacc[2]);
    accum_rs(pB.w, reluB3, vc1, &Racc[3], &Sacc[3]);
    vc1 = V4[(jb + 8 + f) * 32 + dq];      // vc1 dead -> reload in place
    lacc.x += pB.x; lacc.y += pB.y; lacc.z += pB.z; lacc.w += pB.w;
  }

  // ---- epilogue: both R and S staged at once (one sync round) ----
  float4* F4r = (float4*)&red_s[0][0];
  float4* F4s = (float4*)&red_s[1][0];
#pragma unroll
  for (int r = 0; r < TI; ++r) {
    F4r[(f * 4 + r) * 32 + dq] = Racc[r];
    F4s[(f * 4 + r) * 32 + dq] = Sacc[r];
  }
  if (dq == 0) lred4[f] = lacc;
  __syncthreads();
#pragma unroll
  for (int p = 0; p < 4; ++p) {
    const int o = t + 256 * p;       // 0..1023
    const int m = o >> 9;            // 0: R, 1: S (wave-uniform)
    const int r = (o >> 7) & 3;
    const int d = o & 127;
    float acc = 0.f;
#pragma unroll
    for (int c = 0; c < 8; ++c) acc += red_s[m][(c * 4 + r) * 128 + d];
    float* dst = m ? Sw : Rw;
    dst[(jc * N + i0 + r) * DIM + d] = acc;
  }
  if (t < TI) {
    float l = 0.f;
#pragma unroll
    for (int c = 0; c < 8; ++c) l += ((const float*)&lred4[c])[t];
    Lw[jc * N + i0 + t] = l;
  }
}

// ------------------------------------------------------------------
// Kernel 3: combine. 2 rows/block (512 blocks).
// ------------------------------------------------------------------
__global__ __launch_bounds__(256) void attn_combine5(
    const float* __restrict__ WEv, const float* __restrict__ bEv,
    const float* __restrict__ Rw, const float* __restrict__ Sw,
    const float* __restrict__ Lw, float* __restrict__ out) {
  const int i0 = blockIdx.x * 2;
  const int t = threadIdx.x;

  __shared__ __align__(16) float Rst[2][DIM];
  __shared__ __align__(16) float Sst[2][DIM];
  __shared__ __align__(16) float4 Eacc4[8][2][DIM / 4];  // 8 KB
  __shared__ float linv_s[2];

  // step 1: L (lanes 0..7 of wave 0: 2 rows x 4 chunks)
  if (t < 8) {
    const int row = t >> 2, c = t & 3;
    float l = Lw[c * N + i0 + row];
    l += __shfl_xor(l, 1, 4);
    l += __shfl_xor(l, 2, 4);
    if (c == 0) linv_s[row] = 1.0f / l;
  }

  // step 2: R*, S* (512 sums over 256 threads; coalesced over d)
#pragma unroll
  for (int p = 0; p < 2; ++p) {
    const int o = t + 256 * p;
    const int d = o & 127;
    const int set = o >> 7;  // 0..3, wave-uniform
    const int row = set & 1;
    const int mat = set >> 1;
    const float* src = mat ? Sw : Rw;
    float acc = 0.f;
#pragma unroll
    for (int c = 0; c < NCH; ++c) acc += src[(c * N + i0 + row) * DIM + d];
    if (mat) Sst[row][d] = acc; else Rst[row][d] = acc;
  }
  __syncthreads();

  // step 3: matvec R* @ WEv for both rows sharing one WEv load
  {
    const int dq = t & 31;   // output d-quad
    const int qr = t >> 5;   // dp-eighth 0..7
    const float4* WEv4 = (const float4*)WEv;
    float4 a0 = make_float4(0.f, 0.f, 0.f, 0.f);
    float4 a1 = make_float4(0.f, 0.f, 0.f, 0.f);
    const int dp0 = 16 * qr;
#pragma unroll 8
    for (int dp = dp0; dp < dp0 + 16; ++dp) {
      const float4 w4 = WEv4[dp * 32 + dq];  // coalesced float4
      const float r0 = Rst[0][dp];           // LDS broadcast
      const float r1 = Rst[1][dp];
      a0.x = fmaf(r0, w4.x, a0.x); a0.y = fmaf(r0, w4.y, a0.y);
      a0.z = fmaf(r0, w4.z, a0.z); a0.w = fmaf(r0, w4.w, a0.w);
      a1.x = fmaf(r1, w4.x, a1.x); a1.y = fmaf(r1, w4.y, a1.y);
      a1.z = fmaf(r1, w4.z, a1.z); a1.w = fmaf(r1, w4.w, a1.w);
    }
    Eacc4[qr][0][dq] = a0;
    Eacc4[qr][1][dq] = a1;
  }
  __syncthreads();

  // step 4: reduce eighths + normalize + bias + store (1 output/thread)
  {
    const int row = t >> 7, d = t & 127;
    const int dq = d >> 2, e = d & 3;
    float acc = Sst[row][d];
#pragma unroll
    for (int qr = 0; qr < 8; ++qr)
      acc += ((const float*)&Eacc4[qr][row][dq])[e];
    out[(i0 + row) * DIM + d] = fmaf(acc, linv_s[row], bEv[d]);
  }
}

// ------------------------------------------------------------------
// Fallback (round-1 proven kernel) if ws is too small for partials.
// ------------------------------------------------------------------
__global__ __launch_bounds__(256) void attn_fallback(
    const float* __restrict__ Q, const float* __restrict__ K,
    const float* __restrict__ V, const float* __restrict__ WA,
    const float* __restrict__ WEv, const float* __restrict__ bEv,
    float* __restrict__ out) {
  const int i = blockIdx.x;
  const int t = threadIdx.x;

  __shared__ __align__(16) float qs[DIM];
  __shared__ __align__(16) float was[DIM];
  __shared__ __align__(16) float p[N];
  __shared__ float red[256];
  __shared__ __align__(16) float Rs[8][DIM];
  __shared__ __align__(16) float Ss[8][DIM];

  if (t < DIM) {
    qs[t] = Q[i * DIM + t];
    was[t] = WA[t];
  }
  __syncthreads();

  float evals[4];
  float mloc = -3.4e38f;
  for (int jj = 0; jj < 4; ++jj) {
    const int j = t + jj * 256;
    const float4* krow = (const float4*)(K + j * DIM);
    const float4* q4p = (const float4*)qs;
    const float4* w4p = (const float4*)was;
    float acc = 0.f;
    for (int d4 = 0; d4 < DIM / 4; ++d4) {
      const float4 k4 = krow[d4];
      const float4 q4 = q4p[d4];
      const float4 w4 = w4p[d4];
      acc = fmaf(fmaxf(q4.x + k4.x, 0.f), w4.x, acc);
      acc = fmaf(fmaxf(q4.y + k4.y, 0.f), w4.y, acc);
      acc = fmaf(fmaxf(q4.z + k4.z, 0.f), w4.z, acc);
      acc = fmaf(fmaxf(q4.w + k4.w, 0.f), w4.w, acc);
    }
    evals[jj] = acc;
    mloc = fmaxf(mloc, acc);
  }
  red[t] = mloc;
  __syncthreads();
  for (int s = 128; s > 0; s >>= 1) {
    if (t < s) red[t] = fmaxf(red[t], red[t + s]);
    __syncthreads();
  }
  const float m = red[0];
  __syncthreads();
  float lsum = 0.f;
  for (int jj = 0; jj < 4; ++jj) {
    const float pe = __expf(evals[jj] - m);
    p[t + jj * 256] = pe;
    lsum += pe;
  }
  red[t] = lsum;
  __syncthreads();
  for (int s = 128; s > 0; s >>= 1) {
    if (t < s) red[t] += red[t + s];
    __syncthreads();
  }
  const float linv = 1.0f / red[0];
  __syncthreads();

  const int tx = t & 31;
  const int ty = t >> 5;
  const float4 q4 = ((const float4*)qs)[tx];
  float4 R4 = make_float4(0.f, 0.f, 0.f, 0.f);
  float4 S4 = make_float4(0.f, 0.f, 0.f, 0.f);
  for (int j = ty; j < N; j += 8) {
    const float pj = p[j];
    const float4 k4 = ((const float4*)(K + j * DIM))[tx];
    const float4 v4 = ((const float4*)(V + j * DIM))[tx];
    R4.x = fmaf(pj, fmaxf(q4.x + k4.x, 0.f), R4.x);
    R4.y = fmaf(pj, fmaxf(q4.y + k4.y, 0.f), R4.y);
    R4.z = fmaf(pj, fmaxf(q4.z + k4.z, 0.f), R4.z);
    R4.w = fmaf(pj, fmaxf(q4.w + k4.w, 0.f), R4.w);
    S4.x = fmaf(pj, v4.x, S4.x);
    S4.y = fmaf(pj, v4.y, S4.y);
    S4.z = fmaf(pj, v4.z, S4.z);
    S4.w = fmaf(pj, v4.w, S4.w);
  }
  ((float4*)&Rs[ty][0])[tx] = R4;
  ((float4*)&Ss[ty][0])[tx] = S4;
  __syncthreads();

  if (t < DIM) {
    float R = 0.f, S = 0.f;
    for (int g = 0; g < 8; ++g) {
      R += Rs[g][t];
      S += Ss[g][t];
    }
    Rs[0][t] = R;
    Ss[0][t] = S;
  }
  __syncthreads();

  if (t < DIM) {
    float o = Ss[0][t];
    for (int dp = 0; dp < DIM; ++dp) {
      o = fmaf(Rs[0][dp], WEv[dp * DIM + t], o);
    }
    out[i * DIM + t] = fmaf(o, linv, bEv[t]);
  }
}

extern "C" void kernel_launch(void* const* d_in, const int* in_sizes, int n_in,
                              void* d_out, int out_size, void* d_ws, size_t ws_size,
                              hipStream_t stream) {
  const float* x    = (const float*)d_in[0];
  const float* W_Q  = (const float*)d_in[1];
  const float* b_Q  = (const float*)d_in[2];
  const float* W_K  = (const float*)d_in[3];
  const float* b_K  = (const float*)d_in[4];
  const float* W_V  = (const float*)d_in[5];
  const float* b_V  = (const float*)d_in[6];
  const float* W_Ev = (const float*)d_in[7];
  const float* b_Ev = (const float*)d_in[8];
  const float* W_A  = (const float*)d_in[9];
  // d_in[10] = b_A: constant shift under softmax — drops out exactly.

  float* Q = (float*)d_ws;            // N*DIM
  float* K = Q + N * DIM;             // N*DIM
  float* V = K + N * DIM;             // N*DIM
  float* out = (float*)d_out;

  const size_t need_floats = (size_t)3 * N * DIM + (size_t)2 * NCH * N * DIM +
                             (size_t)NCH * N;

  qkv_kernel3<<<N / 4, 512, 0, stream>>>(x, W_Q, b_Q, W_K, b_K, W_V, b_V, Q, K, V);

  if (ws_size >= need_floats * sizeof(float)) {
    float* Rw = V + N * DIM;            // NCH*N*DIM
    float* Sw = Rw + NCH * N * DIM;     // NCH*N*DIM
    float* Lw = Sw + NCH * N * DIM;     // NCH*N
    attn_fused6<<<(N / TI) * NCH, 256, 0, stream>>>(Q, K, V, W_A, Rw, Sw, Lw);
    attn_combine5<<<N / 2, 256, 0, stream>>>(W_Ev, b_Ev, Rw, Sw, Lw, out);
  } else {
    attn_fallback<<<N, 256, 0, stream>>>(Q, K, V, W_A, W_Ev, b_Ev, out);
  }
}

// Round 3
// 105.130 us; speedup vs baseline: 1.1752x; 1.0562x over previous
//
#include <hip/hip_runtime.h>

#define N 1024
#define DIM 128
#define TI 4       // rows per attn block
#define NG 32      // j-groups per block (1024 threads / 32 lanes)
#define NSC 16     // iterations: 64 j's per iter (2 phases x 32 groups)

// ---- DPP 32-lane sum (VALU pipe): group sums land in wave lanes 31 / 63 ----
template <int CTRL>
__device__ __forceinline__ float dpp_add(float x) {
  int y = __builtin_amdgcn_update_dpp(0, __float_as_int(x), CTRL, 0xF, 0xF, true);
  return x + __int_as_float(y);
}
__device__ __forceinline__ float red32(float x) {
  x = dpp_add<0x111>(x);  // row_shr:1
  x = dpp_add<0x112>(x);  // row_shr:2
  x = dpp_add<0x114>(x);  // row_shr:4
  x = dpp_add<0x118>(x);  // row_shr:8
  x = dpp_add<0x142>(x);  // row_bcast15 -> lanes 31/63 have their 32-lane sums
  return x;
}

// Broadcast from lane 31 (lo half) / 63 (hi half): single LDS-pipe op.
__device__ __forceinline__ float bperm(int baddr, float x) {
  return __int_as_float(__builtin_amdgcn_ds_bpermute(baddr, __float_as_int(x)));
}

// e-partial that KEEPS the relu values in registers for the R-accumulation.
__device__ __forceinline__ float epart_keep(const float4 q, const float4 k,
                                            const float4 w, float4* relu) {
  const float rx = fmaxf(q.x + k.x, 0.f);
  const float ry = fmaxf(q.y + k.y, 0.f);
  const float rz = fmaxf(q.z + k.z, 0.f);
  const float rw = fmaxf(q.w + k.w, 0.f);
  relu->x = rx; relu->y = ry; relu->z = rz; relu->w = rw;
  float a = rx * w.x;
  a = fmaf(ry, w.y, a);
  a = fmaf(rz, w.z, a);
  a = fmaf(rw, w.w, a);
  return a;
}

__device__ __forceinline__ void accum_rs(float p, const float4 relu,
                                         const float4 v, float4* R, float4* S) {
  R->x = fmaf(p, relu.x, R->x);
  R->y = fmaf(p, relu.y, R->y);
  R->z = fmaf(p, relu.z, R->z);
  R->w = fmaf(p, relu.w, R->w);
  S->x = fmaf(p, v.x, S->x);
  S->y = fmaf(p, v.y, S->y);
  S->z = fmaf(p, v.z, S->z);
  S->w = fmaf(p, v.w, S->w);
}

// ------------------------------------------------------------------
// Kernel 1: QKV. 4 rows/block, 512 threads, W read ONCE per block.
// ------------------------------------------------------------------
__global__ __launch_bounds__(512) void qkv_kernel3(
    const float* __restrict__ x,
    const float* __restrict__ WQ, const float* __restrict__ bQ,
    const float* __restrict__ WK, const float* __restrict__ bK,
    const float* __restrict__ WV, const float* __restrict__ bV,
    float* __restrict__ Q, float* __restrict__ K, float* __restrict__ V) {
  const int i0 = blockIdx.x * 4;
  const int t = threadIdx.x;
  const int dq = t & 31;   // output d-quad
  const int qr = t >> 5;   // column group 0..15 (8 columns each)

  __shared__ __align__(16) float xs[4][DIM];
  __shared__ __align__(16) float pacc[16][3][4][DIM];  // 96 KB

  if (t < 128) {
    const int row = t >> 5, c4 = t & 31;
    ((float4*)&xs[row][0])[c4] = ((const float4*)(x + (i0 + row) * DIM))[c4];
  }
  __syncthreads();

  const float4* WQ4 = (const float4*)WQ;
  const float4* WK4 = (const float4*)WK;
  const float4* WV4 = (const float4*)WV;
  float4 aQ[4], aK[4], aV[4];
#pragma unroll
  for (int r = 0; r < 4; ++r) {
    aQ[r] = make_float4(0.f, 0.f, 0.f, 0.f);
    aK[r] = make_float4(0.f, 0.f, 0.f, 0.f);
    aV[r] = make_float4(0.f, 0.f, 0.f, 0.f);
  }
  const int c0 = qr * 8;
#pragma unroll 2
  for (int cc = 0; cc < 8; ++cc) {
    const int c = c0 + cc;
    const float4 wq = WQ4[c * 32 + dq];
    const float4 wk = WK4[c * 32 + dq];
    const float4 wv = WV4[c * 32 + dq];
#pragma unroll
    for (int r = 0; r < 4; ++r) {
      const float xv = xs[r][c];
      aQ[r].x = fmaf(xv, wq.x, aQ[r].x); aQ[r].y = fmaf(xv, wq.y, aQ[r].y);
      aQ[r].z = fmaf(xv, wq.z, aQ[r].z); aQ[r].w = fmaf(xv, wq.w, aQ[r].w);
      aK[r].x = fmaf(xv, wk.x, aK[r].x); aK[r].y = fmaf(xv, wk.y, aK[r].y);
      aK[r].z = fmaf(xv, wk.z, aK[r].z); aK[r].w = fmaf(xv, wk.w, aK[r].w);
      aV[r].x = fmaf(xv, wv.x, aV[r].x); aV[r].y = fmaf(xv, wv.y, aV[r].y);
      aV[r].z = fmaf(xv, wv.z, aV[r].z); aV[r].w = fmaf(xv, wv.w, aV[r].w);
    }
  }
#pragma unroll
  for (int r = 0; r < 4; ++r) {
    ((float4*)&pacc[qr][0][r][0])[dq] = aQ[r];
    ((float4*)&pacc[qr][1][r][0])[dq] = aK[r];
    ((float4*)&pacc[qr][2][r][0])[dq] = aV[r];
  }
  __syncthreads();
  {
    const int row = (t >> 7) & 3, d = t & 127;
#pragma unroll
    for (int m = 0; m < 3; ++m) {
      float s = 0.f;
#pragma unroll
      for (int c = 0; c < 16; ++c) s += pacc[c][m][row][d];
      float* dst = (m == 0) ? Q : (m == 1) ? K : V;
      const float* bias = (m == 0) ? bQ : (m == 1) ? bK : bV;
      dst[(i0 + row) * DIM + d] = s + bias[d];
    }
  }
}

// ------------------------------------------------------------------
// Kernel 2 (monolithic): one 1024-thread block per CU handles TI=4
// rows against ALL 1024 j's: no Rw/Sw/Lw partials, no combine kernel.
// 256 blocks = exactly 1/CU; 16 waves/CU — same occupancy as the old
// 4x256-thread layout. Main loop per-wave instruction stream is
// unchanged (VALU-bound core). In-block epilogue: 32-way LDS reduce
// + WEv matvec + softmax normalize + store.
// ------------------------------------------------------------------
__global__ __launch_bounds__(1024) void attn_mono(
    const float* __restrict__ Q, const float* __restrict__ K,
    const float* __restrict__ V, const float* __restrict__ WA,
    const float* __restrict__ WEv, const float* __restrict__ bEv,
    float* __restrict__ out) {
  const int i0 = blockIdx.x * TI;
  const int t = threadIdx.x;
  const int dq = t & 31;           // d-quad lane
  const int f = t >> 5;            // j-group 0..31
  const int baddr = (t & 32) ? (63 << 2) : (31 << 2);

  __shared__ __align__(16) float red_s[2][NG * TI * DIM];  // 128 KB
  __shared__ __align__(16) float4 lred4[NG];               // 512 B
  __shared__ __align__(16) float Rst[TI][DIM];             // 2 KB
  __shared__ __align__(16) float Sst[TI][DIM];             // 2 KB
  __shared__ float linv_s[TI];

  float4 wa4 = ((const float4*)WA)[dq];
  const float LOG2E = 1.44269504088896340736f;
  wa4.x *= LOG2E; wa4.y *= LOG2E; wa4.z *= LOG2E; wa4.w *= LOG2E;

  float4 q4[TI];
#pragma unroll
  for (int r = 0; r < TI; ++r)
    q4[r] = ((const float4*)(Q + (i0 + r) * DIM))[dq];

  float4 Racc[TI], Sacc[TI];
#pragma unroll
  for (int r = 0; r < TI; ++r) {
    Racc[r] = make_float4(0.f, 0.f, 0.f, 0.f);
    Sacc[r] = make_float4(0.f, 0.f, 0.f, 0.f);
  }
  float4 lacc = make_float4(0.f, 0.f, 0.f, 0.f);

  const float4* K4 = (const float4*)K;
  const float4* V4 = (const float4*)V;
  float4 kc0 = K4[(f) * 32 + dq];
  float4 kc1 = K4[(NG + f) * 32 + dq];
  float4 vc0 = V4[(f) * 32 + dq];
  float4 vc1 = V4[(NG + f) * 32 + dq];

  for (int sc = 0; sc < NSC; ++sc) {
    // next sub-chunk base (last iter re-reads itself: in-bounds, harmless)
    const int jb = ((sc + 1 < NSC) ? sc + 1 : sc) * (2 * NG);

    // ---- phase A: j = sc*64 + f ----
    float4 reluA0, reluA1, reluA2, reluA3;
    float4 peA;
    peA.x = epart_keep(q4[0], kc0, wa4, &reluA0);
    peA.y = epart_keep(q4[1], kc0, wa4, &reluA1);
    peA.z = epart_keep(q4[2], kc0, wa4, &reluA2);
    peA.w = epart_keep(q4[3], kc0, wa4, &reluA3);
    kc0 = K4[(jb + f) * 32 + dq];          // kc0 dead -> reload in place

    peA.x = red32(peA.x); peA.y = red32(peA.y);
    peA.z = red32(peA.z); peA.w = red32(peA.w);
    float4 pA;
    pA.x = __builtin_amdgcn_exp2f(bperm(baddr, peA.x));
    pA.y = __builtin_amdgcn_exp2f(bperm(baddr, peA.y));
    pA.z = __builtin_amdgcn_exp2f(bperm(baddr, peA.z));
    pA.w = __builtin_amdgcn_exp2f(bperm(baddr, peA.w));

    accum_rs(pA.x, reluA0, vc0, &Racc[0], &Sacc[0]);
    accum_rs(pA.y, reluA1, vc0, &Racc[1], &Sacc[1]);
    accum_rs(pA.z, reluA2, vc0, &Racc[2], &Sacc[2]);
    accum_rs(pA.w, reluA3, vc0, &Racc[3], &Sacc[3]);
    vc0 = V4[(jb + f) * 32 + dq];          // vc0 dead -> reload in place
    lacc.x += pA.x; lacc.y += pA.y; lacc.z += pA.z; lacc.w += pA.w;

    // ---- phase B: j = sc*64 + 32 + f ----
    float4 reluB0, reluB1, reluB2, reluB3;
    float4 peB;
    peB.x = epart_keep(q4[0], kc1, wa4, &reluB0);
    peB.y = epart_keep(q4[1], kc1, wa4, &reluB1);
    peB.z = epart_keep(q4[2], kc1, wa4, &reluB2);
    peB.w = epart_keep(q4[3], kc1, wa4, &reluB3);
    kc1 = K4[(jb + NG + f) * 32 + dq];     // kc1 dead -> reload in place

    peB.x = red32(peB.x); peB.y = red32(peB.y);
    peB.z = red32(peB.z); peB.w = red32(peB.w);
    float4 pB;
    pB.x = __builtin_amdgcn_exp2f(bperm(baddr, peB.x));
    pB.y = __builtin_amdgcn_exp2f(bperm(baddr, peB.y));
    pB.z = __builtin_amdgcn_exp2f(bperm(baddr, peB.z));
    pB.w = __builtin_amdgcn_exp2f(bperm(baddr, peB.w));

    accum_rs(pB.x, reluB0, vc1, &Racc[0], &Sacc[0]);
    accum_rs(pB.y, reluB1, vc1, &Racc[1], &Sacc[1]);
    accum_rs(pB.z, reluB2, vc1, &Racc[2], &Sacc[2]);
    accum_rs(pB.w, reluB3, vc1, &Racc[3], &Sacc[3]);
    vc1 = V4[(jb + NG + f) * 32 + dq];     // vc1 dead -> reload in place
    lacc.x += pB.x; lacc.y += pB.y; lacc.z += pB.z; lacc.w += pB.w;
  }

  // ---- epilogue step 1: stage Racc/Sacc/lacc ----
  float4* F4r = (float4*)&red_s[0][0];
  float4* F4s = (float4*)&red_s[1][0];
#pragma unroll
  for (int r = 0; r < TI; ++r) {
    F4r[(f * 4 + r) * 32 + dq] = Racc[r];
    F4s[(f * 4 + r) * 32 + dq] = Sacc[r];
  }
  if (dq == 0) lred4[f] = lacc;
  __syncthreads();

  // ---- step 2: 32-way reduce -> Rst/Sst; L -> linv_s ----
  {
    const int m = t >> 9;            // 0: R, 1: S (wave-uniform)
    const int r = (t >> 7) & 3;
    const int d = t & 127;
    float acc = 0.f;
#pragma unroll
    for (int c = 0; c < NG; ++c) acc += red_s[m][(c * 4 + r) * 128 + d];
    if (m) Sst[r][d] = acc; else Rst[r][d] = acc;
  }
  if (t < TI) {
    const float* lf = (const float*)lred4;
    float l = 0.f;
#pragma unroll
    for (int c = 0; c < NG; ++c) l += lf[c * 4 + t];
    linv_s[t] = 1.0f / l;
  }
  __syncthreads();

  // ---- step 3: matvec R* @ WEv (32 dp-groups x 4 dp each) ----
  {
    const int qr = f;                // dp-group 0..31
    const float4* WEv4 = (const float4*)WEv;
    float4 a0 = make_float4(0.f, 0.f, 0.f, 0.f);
    float4 a1 = make_float4(0.f, 0.f, 0.f, 0.f);
    float4 a2 = make_float4(0.f, 0.f, 0.f, 0.f);
    float4 a3 = make_float4(0.f, 0.f, 0.f, 0.f);
    const int dp0 = 4 * qr;
#pragma unroll
    for (int k = 0; k < 4; ++k) {
      const int dp = dp0 + k;
      const float4 w4 = WEv4[dp * 32 + dq];  // coalesced float4
      const float r0 = Rst[0][dp];           // LDS broadcast
      const float r1 = Rst[1][dp];
      const float r2 = Rst[2][dp];
      const float r3 = Rst[3][dp];
      a0.x = fmaf(r0, w4.x, a0.x); a0.y = fmaf(r0, w4.y, a0.y);
      a0.z = fmaf(r0, w4.z, a0.z); a0.w = fmaf(r0, w4.w, a0.w);
      a1.x = fmaf(r1, w4.x, a1.x); a1.y = fmaf(r1, w4.y, a1.y);
      a1.z = fmaf(r1, w4.z, a1.z); a1.w = fmaf(r1, w4.w, a1.w);
      a2.x = fmaf(r2, w4.x, a2.x); a2.y = fmaf(r2, w4.y, a2.y);
      a2.z = fmaf(r2, w4.z, a2.z); a2.w = fmaf(r2, w4.w, a2.w);
      a3.x = fmaf(r3, w4.x, a3.x); a3.y = fmaf(r3, w4.y, a3.y);
      a3.z = fmaf(r3, w4.z, a3.z); a3.w = fmaf(r3, w4.w, a3.w);
    }
    // stage into red_s[0] (raw loop reads done; sync passed)
    float4* Eq = (float4*)&red_s[0][0];
    Eq[(qr * 4 + 0) * 32 + dq] = a0;
    Eq[(qr * 4 + 1) * 32 + dq] = a1;
    Eq[(qr * 4 + 2) * 32 + dq] = a2;
    Eq[(qr * 4 + 3) * 32 + dq] = a3;
  }
  __syncthreads();

  // ---- step 4: reduce dp-groups + normalize + bias + store ----
  if (t < TI * DIM) {
    const int r = t >> 7, d = t & 127;
    float acc = Sst[r][d];
    const float* Ef = &red_s[0][0];
#pragma unroll
    for (int qr = 0; qr < NG; ++qr)
      acc += Ef[(qr * 4 + r) * 128 + d];
    out[(i0 + r) * DIM + d] = fmaf(acc, linv_s[r], bEv[d]);
  }
}

// ------------------------------------------------------------------
// Fallback (round-1 proven kernel) if ws is too small for Q/K/V.
// ------------------------------------------------------------------
__global__ __launch_bounds__(256) void attn_fallback(
    const float* __restrict__ Q, const float* __restrict__ K,
    const float* __restrict__ V, const float* __restrict__ WA,
    const float* __restrict__ WEv, const float* __restrict__ bEv,
    float* __restrict__ out) {
  const int i = blockIdx.x;
  const int t = threadIdx.x;

  __shared__ __align__(16) float qs[DIM];
  __shared__ __align__(16) float was[DIM];
  __shared__ __align__(16) float p[N];
  __shared__ float red[256];
  __shared__ __align__(16) float Rs[8][DIM];
  __shared__ __align__(16) float Ss[8][DIM];

  if (t < DIM) {
    qs[t] = Q[i * DIM + t];
    was[t] = WA[t];
  }
  __syncthreads();

  float evals[4];
  float mloc = -3.4e38f;
  for (int jj = 0; jj < 4; ++jj) {
    const int j = t + jj * 256;
    const float4* krow = (const float4*)(K + j * DIM);
    const float4* q4p = (const float4*)qs;
    const float4* w4p = (const float4*)was;
    float acc = 0.f;
    for (int d4 = 0; d4 < DIM / 4; ++d4) {
      const float4 k4 = krow[d4];
      const float4 q4 = q4p[d4];
      const float4 w4 = w4p[d4];
      acc = fmaf(fmaxf(q4.x + k4.x, 0.f), w4.x, acc);
      acc = fmaf(fmaxf(q4.y + k4.y, 0.f), w4.y, acc);
      acc = fmaf(fmaxf(q4.z + k4.z, 0.f), w4.z, acc);
      acc = fmaf(fmaxf(q4.w + k4.w, 0.f), w4.w, acc);
    }
    evals[jj] = acc;
    mloc = fmaxf(mloc, acc);
  }
  red[t] = mloc;
  __syncthreads();
  for (int s = 128; s > 0; s >>= 1) {
    if (t < s) red[t] = fmaxf(red[t], red[t + s]);
    __syncthreads();
  }
  const float m = red[0];
  __syncthreads();
  float lsum = 0.f;
  for (int jj = 0; jj < 4; ++jj) {
    const float pe = __expf(evals[jj] - m);
    p[t + jj * 256] = pe;
    lsum += pe;
  }
  red[t] = lsum;
  __syncthreads();
  for (int s = 128; s > 0; s >>= 1) {
    if (t < s) red[t] += red[t + s];
    __syncthreads();
  }
  const float linv = 1.0f / red[0];
  __syncthreads();

  const int tx = t & 31;
  const int ty = t >> 5;
  const float4 q4 = ((const float4*)qs)[tx];
  float4 R4 = make_float4(0.f, 0.f, 0.f, 0.f);
  float4 S4 = make_float4(0.f, 0.f, 0.f, 0.f);
  for (int j = ty; j < N; j += 8) {
    const float pj = p[j];
    const float4 k4 = ((const float4*)(K + j * DIM))[tx];
    const float4 v4 = ((const float4*)(V + j * DIM))[tx];
    R4.x = fmaf(pj, fmaxf(q4.x + k4.x, 0.f), R4.x);
    R4.y = fmaf(pj, fmaxf(q4.y + k4.y, 0.f), R4.y);
    R4.z = fmaf(pj, fmaxf(q4.z + k4.z, 0.f), R4.z);
    R4.w = fmaf(pj, fmaxf(q4.w + k4.w, 0.f), R4.w);
    S4.x = fmaf(pj, v4.x, S4.x);
    S4.y = fmaf(pj, v4.y, S4.y);
    S4.z = fmaf(pj, v4.z, S4.z);
    S4.w = fmaf(pj, v4.w, S4.w);
  }
  ((float4*)&Rs[ty][0])[tx] = R4;
  ((float4*)&Ss[ty][0])[tx] = S4;
  __syncthreads();

  if (t < DIM) {
    float R = 0.f, S = 0.f;
    for (int g = 0; g < 8; ++g) {
      R += Rs[g][t];
      S += Ss[g][t];
    }
    Rs[0][t] = R;
    Ss[0][t] = S;
  }
  __syncthreads();

  if (t < DIM) {
    float o = Ss[0][t];
    for (int dp = 0; dp < DIM; ++dp) {
      o = fmaf(Rs[0][dp], WEv[dp * DIM + t], o);
    }
    out[i * DIM + t] = fmaf(o, linv, bEv[t]);
  }
}

extern "C" void kernel_launch(void* const* d_in, const int* in_sizes, int n_in,
                              void* d_out, int out_size, void* d_ws, size_t ws_size,
                              hipStream_t stream) {
  const float* x    = (const float*)d_in[0];
  const float* W_Q  = (const float*)d_in[1];
  const float* b_Q  = (const float*)d_in[2];
  const float* W_K  = (const float*)d_in[3];
  const float* b_K  = (const float*)d_in[4];
  const float* W_V  = (const float*)d_in[5];
  const float* b_V  = (const float*)d_in[6];
  const float* W_Ev = (const float*)d_in[7];
  const float* b_Ev = (const float*)d_in[8];
  const float* W_A  = (const float*)d_in[9];
  // d_in[10] = b_A: constant shift under softmax — drops out exactly.

  float* Q = (float*)d_ws;            // N*DIM
  float* K = Q + N * DIM;             // N*DIM
  float* V = K + N * DIM;             // N*DIM
  float* out = (float*)d_out;

  const size_t need_floats = (size_t)3 * N * DIM;

  qkv_kernel3<<<N / 4, 512, 0, stream>>>(x, W_Q, b_Q, W_K, b_K, W_V, b_V, Q, K, V);

  if (ws_size >= need_floats * sizeof(float)) {
    attn_mono<<<N / TI, 1024, 0, stream>>>(Q, K, V, W_A, W_Ev, b_Ev, out);
  } else {
    attn_fallback<<<N, 256, 0, stream>>>(Q, K, V, W_A, W_Ev, b_Ev, out);
  }
}

// Round 4
// 104.343 us; speedup vs baseline: 1.1841x; 1.0075x over previous
//
#include <hip/hip_runtime.h>

#define N 1024
#define DIM 128
#define TI 4       // rows per attn block
#define NG 32      // j-groups per block (1024 threads / 32 lanes)
#define NSC 16     // iterations: 64 j's per iter (2 phases x 32 groups)

// ---- DPP 32-lane sum (VALU pipe): group sums land in wave lanes 31 / 63 ----
template <int CTRL>
__device__ __forceinline__ float dpp_add(float x) {
  int y = __builtin_amdgcn_update_dpp(0, __float_as_int(x), CTRL, 0xF, 0xF, true);
  return x + __int_as_float(y);
}
__device__ __forceinline__ float red32(float x) {
  x = dpp_add<0x111>(x);  // row_shr:1
  x = dpp_add<0x112>(x);  // row_shr:2
  x = dpp_add<0x114>(x);  // row_shr:4
  x = dpp_add<0x118>(x);  // row_shr:8
  x = dpp_add<0x142>(x);  // row_bcast15 -> lanes 31/63 have their 32-lane sums
  return x;
}

// Broadcast from lane 31 (lo half) / 63 (hi half): single LDS-pipe op.
__device__ __forceinline__ float bperm(int baddr, float x) {
  return __int_as_float(__builtin_amdgcn_ds_bpermute(baddr, __float_as_int(x)));
}

// e-partial that KEEPS the relu values in registers for the R-accumulation.
__device__ __forceinline__ float epart_keep(const float4 q, const float4 k,
                                            const float4 w, float4* relu) {
  const float rx = fmaxf(q.x + k.x, 0.f);
  const float ry = fmaxf(q.y + k.y, 0.f);
  const float rz = fmaxf(q.z + k.z, 0.f);
  const float rw = fmaxf(q.w + k.w, 0.f);
  relu->x = rx; relu->y = ry; relu->z = rz; relu->w = rw;
  float a = rx * w.x;
  a = fmaf(ry, w.y, a);
  a = fmaf(rz, w.z, a);
  a = fmaf(rw, w.w, a);
  return a;
}

__device__ __forceinline__ void accum_rs(float p, const float4 relu,
                                         const float4 v, float4* R, float4* S) {
  R->x = fmaf(p, relu.x, R->x);
  R->y = fmaf(p, relu.y, R->y);
  R->z = fmaf(p, relu.z, R->z);
  R->w = fmaf(p, relu.w, R->w);
  S->x = fmaf(p, v.x, S->x);
  S->y = fmaf(p, v.y, S->y);
  S->z = fmaf(p, v.z, S->z);
  S->w = fmaf(p, v.w, S->w);
}

// ------------------------------------------------------------------
// Kernel 1: QKV. 4 rows/block, 512 threads, W read once per block.
// r4: 2-stage register pipeline — first 12 W-loads issued BEFORE the
// xs barrier (latency hides under x-staging + barrier), second 12
// prefetched while computing the first group. Latency-bound fix.
// ------------------------------------------------------------------
__global__ __launch_bounds__(512) void qkv_kernel4(
    const float* __restrict__ x,
    const float* __restrict__ WQ, const float* __restrict__ bQ,
    const float* __restrict__ WK, const float* __restrict__ bK,
    const float* __restrict__ WV, const float* __restrict__ bV,
    float* __restrict__ Q, float* __restrict__ K, float* __restrict__ V) {
  const int i0 = blockIdx.x * 4;
  const int t = threadIdx.x;
  const int dq = t & 31;   // output d-quad
  const int qr = t >> 5;   // column group 0..15 (8 columns each)

  __shared__ __align__(16) float xs[4][DIM];
  __shared__ __align__(16) float pacc[16][3][4][DIM];  // 96 KB

  const float4* WQ4 = (const float4*)WQ;
  const float4* WK4 = (const float4*)WK;
  const float4* WV4 = (const float4*)WV;
  const int c0 = qr * 8;

  // ---- stage-1 prefetch: columns c0..c0+3 (before the barrier) ----
  float4 wq1[4], wk1[4], wv1[4];
#pragma unroll
  for (int u = 0; u < 4; ++u) {
    wq1[u] = WQ4[(c0 + u) * 32 + dq];
    wk1[u] = WK4[(c0 + u) * 32 + dq];
    wv1[u] = WV4[(c0 + u) * 32 + dq];
  }

  if (t < 128) {
    const int row = t >> 5, c4 = t & 31;
    ((float4*)&xs[row][0])[c4] = ((const float4*)(x + (i0 + row) * DIM))[c4];
  }
  __syncthreads();

  // ---- stage-2 prefetch: columns c0+4..c0+7 ----
  float4 wq2[4], wk2[4], wv2[4];
#pragma unroll
  for (int u = 0; u < 4; ++u) {
    wq2[u] = WQ4[(c0 + 4 + u) * 32 + dq];
    wk2[u] = WK4[(c0 + 4 + u) * 32 + dq];
    wv2[u] = WV4[(c0 + 4 + u) * 32 + dq];
  }

  float4 aQ[4], aK[4], aV[4];
#pragma unroll
  for (int r = 0; r < 4; ++r) {
    aQ[r] = make_float4(0.f, 0.f, 0.f, 0.f);
    aK[r] = make_float4(0.f, 0.f, 0.f, 0.f);
    aV[r] = make_float4(0.f, 0.f, 0.f, 0.f);
  }

  // ---- compute group 1 (loads already in flight ~barrier-long) ----
#pragma unroll
  for (int u = 0; u < 4; ++u) {
    const int c = c0 + u;
#pragma unroll
    for (int r = 0; r < 4; ++r) {
      const float xv = xs[r][c];
      aQ[r].x = fmaf(xv, wq1[u].x, aQ[r].x); aQ[r].y = fmaf(xv, wq1[u].y, aQ[r].y);
      aQ[r].z = fmaf(xv, wq1[u].z, aQ[r].z); aQ[r].w = fmaf(xv, wq1[u].w, aQ[r].w);
      aK[r].x = fmaf(xv, wk1[u].x, aK[r].x); aK[r].y = fmaf(xv, wk1[u].y, aK[r].y);
      aK[r].z = fmaf(xv, wk1[u].z, aK[r].z); aK[r].w = fmaf(xv, wk1[u].w, aK[r].w);
      aV[r].x = fmaf(xv, wv1[u].x, aV[r].x); aV[r].y = fmaf(xv, wv1[u].y, aV[r].y);
      aV[r].z = fmaf(xv, wv1[u].z, aV[r].z); aV[r].w = fmaf(xv, wv1[u].w, aV[r].w);
    }
  }
  // ---- compute group 2 ----
#pragma unroll
  for (int u = 0; u < 4; ++u) {
    const int c = c0 + 4 + u;
#pragma unroll
    for (int r = 0; r < 4; ++r) {
      const float xv = xs[r][c];
      aQ[r].x = fmaf(xv, wq2[u].x, aQ[r].x); aQ[r].y = fmaf(xv, wq2[u].y, aQ[r].y);
      aQ[r].z = fmaf(xv, wq2[u].z, aQ[r].z); aQ[r].w = fmaf(xv, wq2[u].w, aQ[r].w);
      aK[r].x = fmaf(xv, wk2[u].x, aK[r].x); aK[r].y = fmaf(xv, wk2[u].y, aK[r].y);
      aK[r].z = fmaf(xv, wk2[u].z, aK[r].z); aK[r].w = fmaf(xv, wk2[u].w, aK[r].w);
      aV[r].x = fmaf(xv, wv2[u].x, aV[r].x); aV[r].y = fmaf(xv, wv2[u].y, aV[r].y);
      aV[r].z = fmaf(xv, wv2[u].z, aV[r].z); aV[r].w = fmaf(xv, wv2[u].w, aV[r].w);
    }
  }

#pragma unroll
  for (int r = 0; r < 4; ++r) {
    ((float4*)&pacc[qr][0][r][0])[dq] = aQ[r];
    ((float4*)&pacc[qr][1][r][0])[dq] = aK[r];
    ((float4*)&pacc[qr][2][r][0])[dq] = aV[r];
  }
  __syncthreads();
  {
    const int row = (t >> 7) & 3, d = t & 127;
#pragma unroll
    for (int m = 0; m < 3; ++m) {
      float s = 0.f;
#pragma unroll
      for (int c = 0; c < 16; ++c) s += pacc[c][m][row][d];
      float* dst = (m == 0) ? Q : (m == 1) ? K : V;
      const float* bias = (m == 0) ? bQ : (m == 1) ? bK : bV;
      dst[(i0 + row) * DIM + d] = s + bias[d];
    }
  }
}

// ------------------------------------------------------------------
// Kernel 2 (monolithic, r3-proven): one 1024-thread block per CU,
// TI=4 rows vs all 1024 j's. 256 blocks = 1/CU, 16 waves/CU.
// ------------------------------------------------------------------
__global__ __launch_bounds__(1024) void attn_mono(
    const float* __restrict__ Q, const float* __restrict__ K,
    const float* __restrict__ V, const float* __restrict__ WA,
    const float* __restrict__ WEv, const float* __restrict__ bEv,
    float* __restrict__ out) {
  const int i0 = blockIdx.x * TI;
  const int t = threadIdx.x;
  const int dq = t & 31;           // d-quad lane
  const int f = t >> 5;            // j-group 0..31
  const int baddr = (t & 32) ? (63 << 2) : (31 << 2);

  __shared__ __align__(16) float red_s[2][NG * TI * DIM];  // 128 KB
  __shared__ __align__(16) float4 lred4[NG];               // 512 B
  __shared__ __align__(16) float Rst[TI][DIM];             // 2 KB
  __shared__ __align__(16) float Sst[TI][DIM];             // 2 KB
  __shared__ float linv_s[TI];

  float4 wa4 = ((const float4*)WA)[dq];
  const float LOG2E = 1.44269504088896340736f;
  wa4.x *= LOG2E; wa4.y *= LOG2E; wa4.z *= LOG2E; wa4.w *= LOG2E;

  float4 q4[TI];
#pragma unroll
  for (int r = 0; r < TI; ++r)
    q4[r] = ((const float4*)(Q + (i0 + r) * DIM))[dq];

  float4 Racc[TI], Sacc[TI];
#pragma unroll
  for (int r = 0; r < TI; ++r) {
    Racc[r] = make_float4(0.f, 0.f, 0.f, 0.f);
    Sacc[r] = make_float4(0.f, 0.f, 0.f, 0.f);
  }
  float4 lacc = make_float4(0.f, 0.f, 0.f, 0.f);

  const float4* K4 = (const float4*)K;
  const float4* V4 = (const float4*)V;
  float4 kc0 = K4[(f) * 32 + dq];
  float4 kc1 = K4[(NG + f) * 32 + dq];
  float4 vc0 = V4[(f) * 32 + dq];
  float4 vc1 = V4[(NG + f) * 32 + dq];

  for (int sc = 0; sc < NSC; ++sc) {
    // next sub-chunk base (last iter re-reads itself: in-bounds, harmless)
    const int jb = ((sc + 1 < NSC) ? sc + 1 : sc) * (2 * NG);

    // ---- phase A: j = sc*64 + f ----
    float4 reluA0, reluA1, reluA2, reluA3;
    float4 peA;
    peA.x = epart_keep(q4[0], kc0, wa4, &reluA0);
    peA.y = epart_keep(q4[1], kc0, wa4, &reluA1);
    peA.z = epart_keep(q4[2], kc0, wa4, &reluA2);
    peA.w = epart_keep(q4[3], kc0, wa4, &reluA3);
    kc0 = K4[(jb + f) * 32 + dq];          // kc0 dead -> reload in place

    peA.x = red32(peA.x); peA.y = red32(peA.y);
    peA.z = red32(peA.z); peA.w = red32(peA.w);
    float4 pA;
    pA.x = __builtin_amdgcn_exp2f(bperm(baddr, peA.x));
    pA.y = __builtin_amdgcn_exp2f(bperm(baddr, peA.y));
    pA.z = __builtin_amdgcn_exp2f(bperm(baddr, peA.z));
    pA.w = __builtin_amdgcn_exp2f(bperm(baddr, peA.w));

    accum_rs(pA.x, reluA0, vc0, &Racc[0], &Sacc[0]);
    accum_rs(pA.y, reluA1, vc0, &Racc[1], &Sacc[1]);
    accum_rs(pA.z, reluA2, vc0, &Racc[2], &Sacc[2]);
    accum_rs(pA.w, reluA3, vc0, &Racc[3], &Sacc[3]);
    vc0 = V4[(jb + f) * 32 + dq];          // vc0 dead -> reload in place
    lacc.x += pA.x; lacc.y += pA.y; lacc.z += pA.z; lacc.w += pA.w;

    // ---- phase B: j = sc*64 + 32 + f ----
    float4 reluB0, reluB1, reluB2, reluB3;
    float4 peB;
    peB.x = epart_keep(q4[0], kc1, wa4, &reluB0);
    peB.y = epart_keep(q4[1], kc1, wa4, &reluB1);
    peB.z = epart_keep(q4[2], kc1, wa4, &reluB2);
    peB.w = epart_keep(q4[3], kc1, wa4, &reluB3);
    kc1 = K4[(jb + NG + f) * 32 + dq];     // kc1 dead -> reload in place

    peB.x = red32(peB.x); peB.y = red32(peB.y);
    peB.z = red32(peB.z); peB.w = red32(peB.w);
    float4 pB;
    pB.x = __builtin_amdgcn_exp2f(bperm(baddr, peB.x));
    pB.y = __builtin_amdgcn_exp2f(bperm(baddr, peB.y));
    pB.z = __builtin_amdgcn_exp2f(bperm(baddr, peB.z));
    pB.w = __builtin_amdgcn_exp2f(bperm(baddr, peB.w));

    accum_rs(pB.x, reluB0, vc1, &Racc[0], &Sacc[0]);
    accum_rs(pB.y, reluB1, vc1, &Racc[1], &Sacc[1]);
    accum_rs(pB.z, reluB2, vc1, &Racc[2], &Sacc[2]);
    accum_rs(pB.w, reluB3, vc1, &Racc[3], &Sacc[3]);
    vc1 = V4[(jb + NG + f) * 32 + dq];     // vc1 dead -> reload in place
    lacc.x += pB.x; lacc.y += pB.y; lacc.z += pB.z; lacc.w += pB.w;
  }

  // ---- epilogue step 1: stage Racc/Sacc/lacc ----
  float4* F4r = (float4*)&red_s[0][0];
  float4* F4s = (float4*)&red_s[1][0];
#pragma unroll
  for (int r = 0; r < TI; ++r) {
    F4r[(f * 4 + r) * 32 + dq] = Racc[r];
    F4s[(f * 4 + r) * 32 + dq] = Sacc[r];
  }
  if (dq == 0) lred4[f] = lacc;
  __syncthreads();

  // ---- step 2: 32-way reduce -> Rst/Sst; L -> linv_s ----
  {
    const int m = t >> 9;            // 0: R, 1: S (wave-uniform)
    const int r = (t >> 7) & 3;
    const int d = t & 127;
    float acc = 0.f;
#pragma unroll
    for (int c = 0; c < NG; ++c) acc += red_s[m][(c * 4 + r) * 128 + d];
    if (m) Sst[r][d] = acc; else Rst[r][d] = acc;
  }
  if (t < TI) {
    const float* lf = (const float*)lred4;
    float l = 0.f;
#pragma unroll
    for (int c = 0; c < NG; ++c) l += lf[c * 4 + t];
    linv_s[t] = 1.0f / l;
  }
  __syncthreads();

  // ---- step 3: matvec R* @ WEv (32 dp-groups x 4 dp each) ----
  {
    const int qr = f;                // dp-group 0..31
    const float4* WEv4 = (const float4*)WEv;
    float4 a0 = make_float4(0.f, 0.f, 0.f, 0.f);
    float4 a1 = make_float4(0.f, 0.f, 0.f, 0.f);
    float4 a2 = make_float4(0.f, 0.f, 0.f, 0.f);
    float4 a3 = make_float4(0.f, 0.f, 0.f, 0.f);
    const int dp0 = 4 * qr;
#pragma unroll
    for (int k = 0; k < 4; ++k) {
      const int dp = dp0 + k;
      const float4 w4 = WEv4[dp * 32 + dq];  // coalesced float4
      const float r0 = Rst[0][dp];           // LDS broadcast
      const float r1 = Rst[1][dp];
      const float r2 = Rst[2][dp];
      const float r3 = Rst[3][dp];
      a0.x = fmaf(r0, w4.x, a0.x); a0.y = fmaf(r0, w4.y, a0.y);
      a0.z = fmaf(r0, w4.z, a0.z); a0.w = fmaf(r0, w4.w, a0.w);
      a1.x = fmaf(r1, w4.x, a1.x); a1.y = fmaf(r1, w4.y, a1.y);
      a1.z = fmaf(r1, w4.z, a1.z); a1.w = fmaf(r1, w4.w, a1.w);
      a2.x = fmaf(r2, w4.x, a2.x); a2.y = fmaf(r2, w4.y, a2.y);
      a2.z = fmaf(r2, w4.z, a2.z); a2.w = fmaf(r2, w4.w, a2.w);
      a3.x = fmaf(r3, w4.x, a3.x); a3.y = fmaf(r3, w4.y, a3.y);
      a3.z = fmaf(r3, w4.z, a3.z); a3.w = fmaf(r3, w4.w, a3.w);
    }
    // stage into red_s[0] (raw loop reads done; sync passed)
    float4* Eq = (float4*)&red_s[0][0];
    Eq[(qr * 4 + 0) * 32 + dq] = a0;
    Eq[(qr * 4 + 1) * 32 + dq] = a1;
    Eq[(qr * 4 + 2) * 32 + dq] = a2;
    Eq[(qr * 4 + 3) * 32 + dq] = a3;
  }
  __syncthreads();

  // ---- step 4: reduce dp-groups + normalize + bias + store ----
  if (t < TI * DIM) {
    const int r = t >> 7, d = t & 127;
    float acc = Sst[r][d];
    const float* Ef = &red_s[0][0];
#pragma unroll
    for (int qr = 0; qr < NG; ++qr)
      acc += Ef[(qr * 4 + r) * 128 + d];
    out[(i0 + r) * DIM + d] = fmaf(acc, linv_s[r], bEv[d]);
  }
}

// ------------------------------------------------------------------
// Fallback (round-1 proven kernel) if ws is too small for Q/K/V.
// ------------------------------------------------------------------
__global__ __launch_bounds__(256) void attn_fallback(
    const float* __restrict__ Q, const float* __restrict__ K,
    const float* __restrict__ V, const float* __restrict__ WA,
    const float* __restrict__ WEv, const float* __restrict__ bEv,
    float* __restrict__ out) {
  const int i = blockIdx.x;
  const int t = threadIdx.x;

  __shared__ __align__(16) float qs[DIM];
  __shared__ __align__(16) float was[DIM];
  __shared__ __align__(16) float p[N];
  __shared__ float red[256];
  __shared__ __align__(16) float Rs[8][DIM];
  __shared__ __align__(16) float Ss[8][DIM];

  if (t < DIM) {
    qs[t] = Q[i * DIM + t];
    was[t] = WA[t];
  }
  __syncthreads();

  float evals[4];
  float mloc = -3.4e38f;
  for (int jj = 0; jj < 4; ++jj) {
    const int j = t + jj * 256;
    const float4* krow = (const float4*)(K + j * DIM);
    const float4* q4p = (const float4*)qs;
    const float4* w4p = (const float4*)was;
    float acc = 0.f;
    for (int d4 = 0; d4 < DIM / 4; ++d4) {
      const float4 k4 = krow[d4];
      const float4 q4 = q4p[d4];
      const float4 w4 = w4p[d4];
      acc = fmaf(fmaxf(q4.x + k4.x, 0.f), w4.x, acc);
      acc = fmaf(fmaxf(q4.y + k4.y, 0.f), w4.y, acc);
      acc = fmaf(fmaxf(q4.z + k4.z, 0.f), w4.z, acc);
      acc = fmaf(fmaxf(q4.w + k4.w, 0.f), w4.w, acc);
    }
    evals[jj] = acc;
    mloc = fmaxf(mloc, acc);
  }
  red[t] = mloc;
  __syncthreads();
  for (int s = 128; s > 0; s >>= 1) {
    if (t < s) red[t] = fmaxf(red[t], red[t + s]);
    __syncthreads();
  }
  const float m = red[0];
  __syncthreads();
  float lsum = 0.f;
  for (int jj = 0; jj < 4; ++jj) {
    const float pe = __expf(evals[jj] - m);
    p[t + jj * 256] = pe;
    lsum += pe;
  }
  red[t] = lsum;
  __syncthreads();
  for (int s = 128; s > 0; s >>= 1) {
    if (t < s) red[t] += red[t + s];
    __syncthreads();
  }
  const float linv = 1.0f / red[0];
  __syncthreads();

  const int tx = t & 31;
  const int ty = t >> 5;
  const float4 q4 = ((const float4*)qs)[tx];
  float4 R4 = make_float4(0.f, 0.f, 0.f, 0.f);
  float4 S4 = make_float4(0.f, 0.f, 0.f, 0.f);
  for (int j = ty; j < N; j += 8) {
    const float pj = p[j];
    const float4 k4 = ((const float4*)(K + j * DIM))[tx];
    const float4 v4 = ((const float4*)(V + j * DIM))[tx];
    R4.x = fmaf(pj, fmaxf(q4.x + k4.x, 0.f), R4.x);
    R4.y = fmaf(pj, fmaxf(q4.y + k4.y, 0.f), R4.y);
    R4.z = fmaf(pj, fmaxf(q4.z + k4.z, 0.f), R4.z);
    R4.w = fmaf(pj, fmaxf(q4.w + k4.w, 0.f), R4.w);
    S4.x = fmaf(pj, v4.x, S4.x);
    S4.y = fmaf(pj, v4.y, S4.y);
    S4.z = fmaf(pj, v4.z, S4.z);
    S4.w = fmaf(pj, v4.w, S4.w);
  }
  ((float4*)&Rs[ty][0])[tx] = R4;
  ((float4*)&Ss[ty][0])[tx] = S4;
  __syncthreads();

  if (t < DIM) {
    float R = 0.f, S = 0.f;
    for (int g = 0; g < 8; ++g) {
      R += Rs[g][t];
      S += Ss[g][t];
    }
    Rs[0][t] = R;
    Ss[0][t] = S;
  }
  __syncthreads();

  if (t < DIM) {
    float o = Ss[0][t];
    for (int dp = 0; dp < DIM; ++dp) {
      o = fmaf(Rs[0][dp], WEv[dp * DIM + t], o);
    }
    out[i * DIM + t] = fmaf(o, linv, bEv[t]);
  }
}

extern "C" void kernel_launch(void* const* d_in, const int* in_sizes, int n_in,
                              void* d_out, int out_size, void* d_ws, size_t ws_size,
                              hipStream_t stream) {
  const float* x    = (const float*)d_in[0];
  const float* W_Q  = (const float*)d_in[1];
  const float* b_Q  = (const float*)d_in[2];
  const float* W_K  = (const float*)d_in[3];
  const float* b_K  = (const float*)d_in[4];
  const float* W_V  = (const float*)d_in[5];
  const float* b_V  = (const float*)d_in[6];
  const float* W_Ev = (const float*)d_in[7];
  const float* b_Ev = (const float*)d_in[8];
  const float* W_A  = (const float*)d_in[9];
  // d_in[10] = b_A: constant shift under softmax — drops out exactly.

  float* Q = (float*)d_ws;            // N*DIM
  float* K = Q + N * DIM;             // N*DIM
  float* V = K + N * DIM;             // N*DIM
  float* out = (float*)d_out;

  const size_t need_floats = (size_t)3 * N * DIM;

  qkv_kernel4<<<N / 4, 512, 0, stream>>>(x, W_Q, b_Q, W_K, b_K, W_V, b_V, Q, K, V);

  if (ws_size >= need_floats * sizeof(float)) {
    attn_mono<<<N / TI, 1024, 0, stream>>>(Q, K, V, W_A, W_Ev, b_Ev, out);
  } else {
    attn_fallback<<<N, 256, 0, stream>>>(Q, K, V, W_A, W_Ev, b_Ev, out);
  }
}